// Round 14
// baseline (198.826 us; speedup 1.0000x reference)
//
#include <hip/hip_runtime.h>
#include <hip/hip_bf16.h>
#include <stdint.h>

typedef unsigned short u16;
typedef __attribute__((ext_vector_type(8))) short bf16x8;
typedef __attribute__((ext_vector_type(4))) short bf16x4;
typedef __attribute__((ext_vector_type(4))) float f32x4;

#define DEV static __device__ __forceinline__

DEV u16 f2bf(float f){
  union { float f; unsigned u; } x; x.f = f;
  unsigned r = x.u + 0x7fffu + ((x.u >> 16) & 1u);
  return (u16)(r >> 16);
}

DEV float bf2f(u16 u){
  union { unsigned u; float f; } x; x.u = ((unsigned)u) << 16; return x.f;
}

DEV bf16x8 ldfrag(const u16* p){           // two ds_read_b64 (8B-aligned rows)
  bf16x4 a = *(const bf16x4*)p;
  bf16x4 b = *(const bf16x4*)(p+4);
  bf16x8 r;
  r[0]=a[0]; r[1]=a[1]; r[2]=a[2]; r[3]=a[3];
  r[4]=b[0]; r[5]=b[1]; r[6]=b[2]; r[7]=b[3];
  return r;
}

DEV bf16x4 cvt4(float a, float b, float c, float d){
  bf16x4 r; r[0]=(short)f2bf(a); r[1]=(short)f2bf(b); r[2]=(short)f2bf(c); r[3]=(short)f2bf(d);
  return r;
}

DEV void g2l16(const void* g, void* l){
  __builtin_amdgcn_global_load_lds((const __attribute__((address_space(1))) unsigned int*)g,
                                   (__attribute__((address_space(3))) unsigned int*)l,
                                   16, 0, 0);
}

// ---- fused transposes: z=0..4 big 2048x2048, z=5 hX convert, z=6..9 small mats,
// ---- z=10 WbT rows 256..383 of WfgT (rows>=16 zero-padded) ----
__global__ __launch_bounds__(256)
void transp64_k(const float* __restrict__ Wq, const float* __restrict__ Wk,
                const float* __restrict__ Wv, const float* __restrict__ Ww,
                const float* __restrict__ Wo, u16* __restrict__ WcatT, u16* __restrict__ WoT,
                const float* __restrict__ hX, u16* __restrict__ h_bf,
                const float* __restrict__ Wf1, const float* __restrict__ Wg1,
                const float* __restrict__ Wf2, const float* __restrict__ Wg2,
                const float* __restrict__ Wb,
                u16* __restrict__ WfgT, u16* __restrict__ Wf2T, u16* __restrict__ Wg2T){
  __shared__ float tile[64*65];
  const int z = blockIdx.z;
  if (z == 5){
    int idx = ((blockIdx.y*32 + blockIdx.x)*256 + threadIdx.x)*8;
    float4 v0 = *(const float4*)&hX[idx];
    float4 v1 = *(const float4*)&hX[idx+4];
    ushort4 o0, o1;
    o0.x=f2bf(v0.x); o0.y=f2bf(v0.y); o0.z=f2bf(v0.z); o0.w=f2bf(v0.w);
    o1.x=f2bf(v1.x); o1.y=f2bf(v1.y); o1.z=f2bf(v1.z); o1.w=f2bf(v1.w);
    *(ushort4*)&h_bf[idx]   = o0;
    *(ushort4*)&h_bf[idx+4] = o1;
    return;
  }
  if (z == 10){
    int rem = blockIdx.y*32 + blockIdx.x;
    if (rem >= 256) return;
    int cx = rem & 63, cy = rem >> 6;     // k-tile (2048/32), row-tile (128/32)
    const int x = threadIdx.x & 31, y0 = threadIdx.x >> 5;
    int k = cx*32 + x;
#pragma unroll
    for (int j=0;j<4;j++){
      int rpad = cy*32 + y0 + j*8;        // 0..127 -> WfgT row 256+rpad
      float v = (rpad < 16) ? Wb[(size_t)k*16 + rpad] : 0.f;
      WfgT[(size_t)(256+rpad)*2048 + k] = f2bf(v);
    }
    return;
  }
  if (z >= 6){
    int rem = blockIdx.y*32 + blockIdx.x;
    if (rem >= 256) return;
    const float* src; u16* dst; int R, C, cx, cy;
    if (z==6){      src=Wf1; dst=WfgT;                  R=2048; C=128;  cx=rem&3;  cy=rem>>2; }
    else if (z==7){ src=Wg1; dst=WfgT+(size_t)128*2048; R=2048; C=128;  cx=rem&3;  cy=rem>>2; }
    else if (z==8){ src=Wf2; dst=Wf2T;                  R=128;  C=2048; cx=rem>>2; cy=rem&3; }
    else {          src=Wg2; dst=Wg2T;                  R=128;  C=2048; cx=rem>>2; cy=rem&3; }
    const int c0 = cx*32, r0 = cy*32;
    const int x = threadIdx.x & 31, y0 = threadIdx.x >> 5;
#pragma unroll
    for (int j=0;j<4;j++){
      int r = y0 + j*8;
      tile[r*33 + x] = src[(size_t)(r0+r)*C + c0 + x];
    }
    __syncthreads();
#pragma unroll
    for (int j=0;j<4;j++){
      int cc = y0 + j*8;
      dst[(size_t)(c0+cc)*R + r0 + x] = f2bf(tile[x*33 + cc]);
    }
    return;
  }
  const float* src = (z==0)?Wq:((z==1)?Wk:((z==2)?Wv:((z==3)?Ww:Wo)));
  u16* dst = (z<4) ? (WcatT + (size_t)z*4194304) : WoT;
  const int c0 = blockIdx.x*64, r0 = blockIdx.y*64;
#pragma unroll
  for (int p=0;p<4;p++){
    int i = threadIdx.x + p*256;
    int r = i>>4, c4 = (i&15)<<2;
    *(float4*)&tile[r*65 + c4] = *(const float4*)&src[(size_t)(r0+r)*2048 + c0 + c4];
  }
  __syncthreads();
#pragma unroll
  for (int p=0;p<4;p++){
    int i = threadIdx.x + p*256;
    int cc = i>>4, r4 = (i&15)<<2;
    ushort4 o;
    o.x = f2bf(tile[(r4+0)*65 + cc]); o.y = f2bf(tile[(r4+1)*65 + cc]);
    o.z = f2bf(tile[(r4+2)*65 + cc]); o.w = f2bf(tile[(r4+3)*65 + cc]);
    *(ushort4*)&dst[(size_t)(c0+cc)*2048 + r0 + r4] = o;
  }
}

// ---- G1 fused GEMM: M=1024, N=8576 (8192 qkvw + 384 f1g1/beta), K=2048 ----
// 128x128 tile, BK=64, 4 waves, dbuf + counted vmcnt; epilogue splits outputs
__global__ __launch_bounds__(256)
void gemmQ_k(const u16* __restrict__ A, const u16* __restrict__ B, u16* __restrict__ C,
             u16* __restrict__ f1g1o, float* __restrict__ betab,
             int K, int lda, int ldb){
  __shared__ u16 As[2][128*64];
  __shared__ u16 Bs[2][128*64];
  const int m0 = blockIdx.y*128, n0 = blockIdx.x*128;
  const int tid = threadIdx.x;
  const int wave = tid>>6, lane = tid&63, lr = lane&15, kg = lane>>4;
  const int wm = wave>>1, wn = wave&1;
  const f32x4 vz = {0.f,0.f,0.f,0.f};
  f32x4 acc[4][4];
#pragma unroll
  for (int a=0;a<4;a++)
#pragma unroll
    for (int b=0;b<4;b++) acc[a][b]=vz;

#define STAGE4(buf, k0) do { \
    _Pragma("unroll") \
    for (int p=0;p<4;p++){ \
      int chunk = tid + p*256, r_ = chunk>>3, ci = chunk&7; \
      g2l16(A + (size_t)(m0+r_)*lda + (k0) + ((ci^(r_&7))<<3), &As[buf][chunk*8]); \
    } \
    _Pragma("unroll") \
    for (int p=0;p<4;p++){ \
      int chunk = tid + p*256, r_ = chunk>>3, ci = chunk&7; \
      g2l16(B + (size_t)(n0+r_)*ldb + (k0) + ((ci^(r_&7))<<3), &Bs[buf][chunk*8]); \
    } \
  } while(0)

  const int nt = K>>6;          // >= 2 required
  STAGE4(0, 0);
  STAGE4(1, 64);
  for (int t=0; t<nt; ++t){
    const int buf = t&1;
    if (t < nt-1) asm volatile("s_waitcnt vmcnt(8)" ::: "memory");
    else          asm volatile("s_waitcnt vmcnt(0)" ::: "memory");
    asm volatile("s_barrier" ::: "memory");
#pragma unroll
    for (int ks=0; ks<2; ++ks){
      bf16x8 af[4], bfv[4];
#pragma unroll
      for (int mi=0;mi<4;mi++){
        int r = wm*64+mi*16+lr;
        af[mi] = *(const bf16x8*)&As[buf][r*64 + (((ks*4+kg)^(r&7))<<3)];
      }
#pragma unroll
      for (int ni=0;ni<4;ni++){
        int r = wn*64+ni*16+lr;
        bfv[ni] = *(const bf16x8*)&Bs[buf][r*64 + (((ks*4+kg)^(r&7))<<3)];
      }
      asm volatile("s_waitcnt lgkmcnt(0)" ::: "memory");
      __builtin_amdgcn_sched_barrier(0);
      __builtin_amdgcn_s_setprio(1);
#pragma unroll
      for (int mi=0;mi<4;mi++)
#pragma unroll
        for (int ni=0;ni<4;ni++)
          acc[mi][ni] = __builtin_amdgcn_mfma_f32_16x16x32_bf16(af[mi], bfv[ni], acc[mi][ni], 0, 0, 0);
      __builtin_amdgcn_s_setprio(0);
      __builtin_amdgcn_sched_barrier(0);
      asm volatile("s_barrier" ::: "memory");
    }
    if (t+2 < nt) STAGE4(buf, (t+2)<<6);
  }
#undef STAGE4
#pragma unroll
  for (int mi=0;mi<4;mi++)
#pragma unroll
    for (int ni=0;ni<4;ni++)
#pragma unroll
      for (int vv=0;vv<4;vv++){
        int row = m0 + wm*64 + mi*16 + kg*4 + vv;
        int col = n0 + wn*64 + ni*16 + lr;
        float val = acc[mi][ni][vv];
        if (col < 8192){
          C[(size_t)row*8192 + col] = f2bf(val);
        } else {
          int c8 = col - 8192;
          f1g1o[(size_t)row*384 + c8] = f2bf(val);
          if (c8 >= 256 && c8 < 272)
            betab[row*16 + (c8-256)] = 1.f/(1.f+__expf(-val));
        }
      }
}

// ---- split-K pipelined GEMM: 128x128, BK=64 -> atomic f32 accumulate into out ----
__global__ __launch_bounds__(256)
void gemm4sk_k(const u16* __restrict__ A, const u16* __restrict__ B, float* __restrict__ out,
               int Khalf, int lda, int ldb, int ldc){
  __shared__ u16 As[2][128*64];
  __shared__ u16 Bs[2][128*64];
  const int m0 = blockIdx.y*128, n0 = blockIdx.x*128;
  const int kbase = blockIdx.z*Khalf;
  const int tid = threadIdx.x;
  const int wave = tid>>6, lane = tid&63, lr = lane&15, kg = lane>>4;
  const int wm = wave>>1, wn = wave&1;
  const f32x4 vz = {0.f,0.f,0.f,0.f};
  f32x4 acc[4][4];
#pragma unroll
  for (int a=0;a<4;a++)
#pragma unroll
    for (int b=0;b<4;b++) acc[a][b]=vz;

#define STAGE4(buf, k0) do { \
    _Pragma("unroll") \
    for (int p=0;p<4;p++){ \
      int chunk = tid + p*256, r_ = chunk>>3, ci = chunk&7; \
      g2l16(A + (size_t)(m0+r_)*lda + (k0) + ((ci^(r_&7))<<3), &As[buf][chunk*8]); \
    } \
    _Pragma("unroll") \
    for (int p=0;p<4;p++){ \
      int chunk = tid + p*256, r_ = chunk>>3, ci = chunk&7; \
      g2l16(B + (size_t)(n0+r_)*ldb + (k0) + ((ci^(r_&7))<<3), &Bs[buf][chunk*8]); \
    } \
  } while(0)

  const int nt = Khalf>>6;      // >= 2 required
  STAGE4(0, kbase);
  STAGE4(1, kbase+64);
  for (int t=0; t<nt; ++t){
    const int buf = t&1;
    if (t < nt-1) asm volatile("s_waitcnt vmcnt(8)" ::: "memory");
    else          asm volatile("s_waitcnt vmcnt(0)" ::: "memory");
    asm volatile("s_barrier" ::: "memory");
#pragma unroll
    for (int ks=0; ks<2; ++ks){
      bf16x8 af[4], bfv[4];
#pragma unroll
      for (int mi=0;mi<4;mi++){
        int r = wm*64+mi*16+lr;
        af[mi] = *(const bf16x8*)&As[buf][r*64 + (((ks*4+kg)^(r&7))<<3)];
      }
#pragma unroll
      for (int ni=0;ni<4;ni++){
        int r = wn*64+ni*16+lr;
        bfv[ni] = *(const bf16x8*)&Bs[buf][r*64 + (((ks*4+kg)^(r&7))<<3)];
      }
      asm volatile("s_waitcnt lgkmcnt(0)" ::: "memory");
      __builtin_amdgcn_sched_barrier(0);
      __builtin_amdgcn_s_setprio(1);
#pragma unroll
      for (int mi=0;mi<4;mi++)
#pragma unroll
        for (int ni=0;ni<4;ni++)
          acc[mi][ni] = __builtin_amdgcn_mfma_f32_16x16x32_bf16(af[mi], bfv[ni], acc[mi][ni], 0, 0, 0);
      __builtin_amdgcn_s_setprio(0);
      __builtin_amdgcn_sched_barrier(0);
      asm volatile("s_barrier" ::: "memory");
    }
    if (t+2 < nt) STAGE4(buf, kbase + ((t+2)<<6));
  }
#undef STAGE4
  // 2 contributions per address (z=0,1); f32 add is commutative -> deterministic
#pragma unroll
  for (int mi=0;mi<4;mi++)
#pragma unroll
    for (int ni=0;ni<4;ni++)
#pragma unroll
      for (int vv=0;vv<4;vv++){
        int row = m0 + wm*64 + mi*16 + kg*4 + vv;
        int col = n0 + wn*64 + ni*16 + lr;
        unsafeAtomicAdd(&out[(size_t)row*ldc + col], acc[mi][ni][vv]);
      }
}

// ---- fused dual gate GEMM (128^2, K=128): z=0 -> logsigmoid+chunk-cumsum -> cgb f32 ;
//      z=1 -> gate -> bf16 ----
__global__ __launch_bounds__(256)
void gemmg_k(const u16* __restrict__ f1g1, const u16* __restrict__ Bf, const u16* __restrict__ Bg,
             float* __restrict__ Ccg, u16* __restrict__ Cgate){
  __shared__ u16 As[128*32];
  __shared__ u16 Bs[128*32];
  const int zz = blockIdx.z;
  const u16* A = f1g1 + zz*128;          // lda = 384
  const u16* B = zz ? Bg : Bf;           // ldb = 128
  const int m0 = blockIdx.y*128, n0 = blockIdx.x*128;
  const int tid = threadIdx.x;
  const int lane = tid & 63, wave = tid >> 6;
  const int wr = wave >> 1, wc = wave & 1;
  const int lr = lane & 15, kg = lane >> 4;
  const f32x4 vzero = {0.f,0.f,0.f,0.f};
  f32x4 acc[4][4];
#pragma unroll
  for (int a=0;a<4;a++)
#pragma unroll
    for (int b=0;b<4;b++) acc[a][b] = vzero;
  const int r0 = tid>>2, s0 = tid&3;
  for (int k0=0;k0<128;k0+=32){
    __syncthreads();
    g2l16(A + (size_t)(m0+r0)*384 + k0 + s0*8, (u16*)As + (size_t)tid*8);
    g2l16(B + (size_t)(n0+r0)*128 + k0 + s0*8, (u16*)Bs + (size_t)tid*8);
    g2l16(A + (size_t)(m0+r0+64)*384 + k0 + s0*8, (u16*)As + (size_t)(tid+256)*8);
    g2l16(B + (size_t)(n0+r0+64)*128 + k0 + s0*8, (u16*)Bs + (size_t)(tid+256)*8);
    __syncthreads();
    bf16x8 af[4], bfv[4];
#pragma unroll
    for (int mi=0;mi<4;mi++) af[mi]  = *(const bf16x8*)(As + (wr*64+mi*16+lr)*32 + kg*8);
#pragma unroll
    for (int ni=0;ni<4;ni++) bfv[ni] = *(const bf16x8*)(Bs + (wc*64+ni*16+lr)*32 + kg*8);
#pragma unroll
    for (int mi=0;mi<4;mi++)
#pragma unroll
      for (int ni=0;ni<4;ni++)
        acc[mi][ni] = __builtin_amdgcn_mfma_f32_16x16x32_bf16(af[mi], bfv[ni], acc[mi][ni], 0, 0, 0);
  }
  if (zz == 0){
    // logsigmoid + inclusive cumsum over the 64-row chunk (wr-aligned) per column
#pragma unroll
    for (int ni=0;ni<4;ni++){
      float p[4][4]; float s[4];
#pragma unroll
      for (int mi=0;mi<4;mi++){
        float run = 0.f;
#pragma unroll
        for (int vv=0;vv<4;vv++){
          float v = acc[mi][ni][vv];
          v = fminf(v,0.f) - __logf(1.f + __expf(-fabsf(v)));
          run += v; p[mi][vv] = run;
        }
        s[mi] = run;
      }
      float M = 0.f; float base[4];
#pragma unroll
      for (int mi=0;mi<4;mi++){
        float a0 = __shfl(s[mi], lr);
        float a1 = __shfl(s[mi], lr+16);
        float a2 = __shfl(s[mi], lr+32);
        float a3 = __shfl(s[mi], lr+48);
        float before = 0.f;
        if (kg>0) before += a0;
        if (kg>1) before += a1;
        if (kg>2) before += a2;
        base[mi] = M + before;
        M += a0+a1+a2+a3;
      }
#pragma unroll
      for (int mi=0;mi<4;mi++)
#pragma unroll
        for (int vv=0;vv<4;vv++){
          int row = m0 + wr*64 + mi*16 + kg*4 + vv;
          int col = n0 + wc*64 + ni*16 + lr;
          Ccg[(size_t)row*2048 + col] = base[mi] + p[mi][vv];
        }
    }
  } else {
#pragma unroll
    for (int mi=0;mi<4;mi++)
#pragma unroll
      for (int ni=0;ni<4;ni++)
#pragma unroll
        for (int vv=0;vv<4;vv++){
          int row = m0 + wr*64 + mi*16 + kg*4 + vv;
          int col = n0 + wc*64 + ni*16 + lr;
          Cgate[(size_t)row*2048 + col] = f2bf(acc[mi][ni][vv]);
        }
  }
}

// ---- causal conv4 + silu, 8 ch/thread: q,k,v -> bf16 ; w-branch -> l2norm*beta -> bwb bf16 ----
__global__ __launch_bounds__(256)
void conv_k(const u16* __restrict__ raw, const float* __restrict__ cq,
            const float* __restrict__ ck, const float* __restrict__ cv,
            const float* __restrict__ betab,
            u16* __restrict__ qo, u16* __restrict__ ko,
            u16* __restrict__ vo, u16* __restrict__ bwout){
  int idx = blockIdx.x*256 + threadIdx.x;      // 262144 total
  int g8 = idx & 1023;                          // channel-group (8 ch)
  int tb = idx >> 10;                           // t-block, t0 = tb*4
  int chg = g8*8;
  int which = chg >> 11, cc = chg & 2047;
  const float* wt = (which==0)?cq:((which==1)?ck:cv);   // w-branch (3) uses cv (faithful to ref)
  float w[8][4];
#pragma unroll
  for (int e=0;e<8;e++){
    float4 w4 = *(const float4*)&wt[(cc+e)*4];
    w[e][0]=w4.x; w[e][1]=w4.y; w[e][2]=w4.z; w[e][3]=w4.w;
  }
  int t0 = tb*4;
  float x[7][8];
#pragma unroll
  for (int j=0;j<7;j++){
    int t = t0 - 3 + j;
    if (t >= 0){
      bf16x8 xv = *(const bf16x8*)&raw[(size_t)t*8192 + chg];
#pragma unroll
      for (int e=0;e<8;e++) x[j][e] = bf2f((u16)xv[e]);
    } else {
#pragma unroll
      for (int e=0;e<8;e++) x[j][e] = 0.f;
    }
  }
  float y[4][8];
#pragma unroll
  for (int j=0;j<4;j++)
#pragma unroll
    for (int e=0;e<8;e++){
      float a = x[j][e]*w[e][0] + x[j+1][e]*w[e][1] + x[j+2][e]*w[e][2] + x[j+3][e]*w[e][3];
      y[j][e] = a/(1.f+__expf(-a));             // silu
    }
  if (which < 3){
    u16* outb = (which==0)?qo:((which==1)?ko:vo);
#pragma unroll
    for (int j=0;j<4;j++){
      bf16x8 o;
#pragma unroll
      for (int e=0;e<8;e++) o[e] = (short)f2bf(y[j][e]);
      *(bf16x8*)&outb[(size_t)(t0+j)*2048 + cc] = o;
    }
  } else {
    // l2norm over head (128 ch = 16 lanes x 8): shfl within aligned 16-lane group
    const int h = cc >> 7;
#pragma unroll
    for (int j=0;j<4;j++){
      float s = 0.f;
#pragma unroll
      for (int e=0;e<8;e++) s += y[j][e]*y[j][e];
      s += __shfl_xor(s,1); s += __shfl_xor(s,2);
      s += __shfl_xor(s,4); s += __shfl_xor(s,8);
      float r = rsqrtf(s + 1e-6f) * betab[(t0+j)*16 + h];
      bf16x8 o;
#pragma unroll
      for (int e=0;e<8;e++) o[e] = (short)f2bf(y[j][e]*r);
      *(bf16x8*)&bwout[(size_t)(t0+j)*2048 + cc] = o;
    }
  }
}

// ---------------- Phase A (MFMA): DSkT[m][d] = U^T K ; DSvT[v][m] = V^T U (bf16 out) ----------------
__global__ __launch_bounds__(256)
void phaseA_k(const u16* __restrict__ k, const u16* __restrict__ v,
              const u16* __restrict__ bw, const float* __restrict__ cg,
              u16* __restrict__ DSkT, u16* __restrict__ DSvT){
  __shared__ u16 UT[128*68];
  __shared__ u16 KT[128*68];
  __shared__ u16 VT[128*68];
  __shared__ float Gt[128];
  const int bx=blockIdx.x, h=bx&15, c=bx>>4, tid=threadIdx.x;
  const int w=tid>>6, lane=tid&63, lr=lane&15, kg=lane>>4;
  if (tid<128) Gt[tid] = cg[(size_t)(c*64+63)*2048 + h*128 + tid];
  __syncthreads();
#pragma unroll
  for (int j=0;j<8;j++){
    int f4=tid+j*256, r=f4>>5, c4=(f4&31)<<2;
    size_t g=(size_t)(c*64+r)*2048 + h*128 + c4;
    ushort4 kv=*(const ushort4*)&k[g];
    ushort4 vv=*(const ushort4*)&v[g];
    ushort4 bv=*(const ushort4*)&bw[g];
    float4 cv=*(const float4*)&cg[g];
    float u0=bf2f(bv.x)*__expf(Gt[c4+0]-cv.x);
    float u1=bf2f(bv.y)*__expf(Gt[c4+1]-cv.y);
    float u2=bf2f(bv.z)*__expf(Gt[c4+2]-cv.z);
    float u3=bf2f(bv.w)*__expf(Gt[c4+3]-cv.w);
    KT[(c4+0)*68+r]=kv.x; KT[(c4+1)*68+r]=kv.y;
    KT[(c4+2)*68+r]=kv.z; KT[(c4+3)*68+r]=kv.w;
    VT[(c4+0)*68+r]=vv.x; VT[(c4+1)*68+r]=vv.y;
    VT[(c4+2)*68+r]=vv.z; VT[(c4+3)*68+r]=vv.w;
    UT[(c4+0)*68+r]=f2bf(u0);   UT[(c4+1)*68+r]=f2bf(u1);
    UT[(c4+2)*68+r]=f2bf(u2);   UT[(c4+3)*68+r]=f2bf(u3);
  }
  __syncthreads();
  const f32x4 vz = {0.f,0.f,0.f,0.f};
  {
    f32x4 acc[2][8];
#pragma unroll
    for (int a=0;a<2;a++)
#pragma unroll
      for (int b=0;b<8;b++) acc[a][b]=vz;
#pragma unroll
    for (int ks=0;ks<2;ks++){
      bf16x8 a0=ldfrag(&UT[(w*32   +lr)*68 + ks*32+kg*8]);
      bf16x8 a1=ldfrag(&UT[(w*32+16+lr)*68 + ks*32+kg*8]);
#pragma unroll
      for (int nj=0;nj<8;nj++){
        bf16x8 b=ldfrag(&KT[(nj*16+lr)*68 + ks*32+kg*8]);
        acc[0][nj]=__builtin_amdgcn_mfma_f32_16x16x32_bf16(a0,b,acc[0][nj],0,0,0);
        acc[1][nj]=__builtin_amdgcn_mfma_f32_16x16x32_bf16(a1,b,acc[1][nj],0,0,0);
      }
    }
#pragma unroll
    for (int mi2=0;mi2<2;mi2++)
#pragma unroll
      for (int nj=0;nj<8;nj++)
#pragma unroll
        for (int vv2=0;vv2<4;vv2++)
          DSkT[(size_t)bx*16384 + (size_t)(w*32+mi2*16+kg*4+vv2)*128 + nj*16+lr] = f2bf(acc[mi2][nj][vv2]);
  }
  {
    f32x4 acc[2][8];
#pragma unroll
    for (int a=0;a<2;a++)
#pragma unroll
      for (int b=0;b<8;b++) acc[a][b]=vz;
#pragma unroll
    for (int ks=0;ks<2;ks++){
      bf16x8 a0=ldfrag(&VT[(w*32   +lr)*68 + ks*32+kg*8]);
      bf16x8 a1=ldfrag(&VT[(w*32+16+lr)*68 + ks*32+kg*8]);
#pragma unroll
      for (int nj=0;nj<8;nj++){
        bf16x8 b=ldfrag(&UT[(nj*16+lr)*68 + ks*32+kg*8]);
        acc[0][nj]=__builtin_amdgcn_mfma_f32_16x16x32_bf16(a0,b,acc[0][nj],0,0,0);
        acc[1][nj]=__builtin_amdgcn_mfma_f32_16x16x32_bf16(a1,b,acc[1][nj],0,0,0);
      }
    }
#pragma unroll
    for (int mi2=0;mi2<2;mi2++)
#pragma unroll
      for (int nj=0;nj<8;nj++)
#pragma unroll
        for (int vv2=0;vv2<4;vv2++)
          DSvT[(size_t)bx*16384 + (size_t)(w*32+mi2*16+kg*4+vv2)*128 + nj*16+lr] = f2bf(acc[mi2][nj][vv2]);
  }
}

// ---------------- Phase B: sequential cross-chunk combine (bf16 in/out) ----------------
__global__ __launch_bounds__(256)
void phaseB_k(const u16* __restrict__ DSk, const u16* __restrict__ DSv,
              const float* __restrict__ cg, u16* __restrict__ Sk0, u16* __restrict__ Sv0){
  unsigned idx = blockIdx.x*256u + threadIdx.x;   // 524288 total
  int sel  = idx >> 18;
  int h    = (idx >> 14) & 15;
  int flat = idx & 16383;                 // SkT: m*128+d ; SvT: v*128+m
  int mdec = sel ? (flat & 127) : (flat >> 7);
  const u16* DS = sel ? DSv : DSk;
  u16* S = sel ? Sv0 : Sk0;
  float cur = 0.f;
  for (int c=0;c<16;c++){
    size_t sb = ((size_t)(c*16+h))*16384 + flat;
    S[sb] = f2bf(cur);                     // state BEFORE chunk c
    float gd = __expf(cg[(size_t)(c*64+63)*2048 + h*128 + mdec]);
    cur = cur*gd + bf2f(DS[sb]);
  }
}

// ---------------- Phase C (MFMA): per-chunk outputs + fused gated RMSNorm -> Obf ----------------
__global__ __launch_bounds__(256)
void phaseC_k(const u16* __restrict__ q, const u16* __restrict__ k,
              const u16* __restrict__ v, const u16* __restrict__ bw,
              const float* __restrict__ cg, const u16* __restrict__ SkT,
              const u16* __restrict__ SvT, const u16* __restrict__ gate,
              const float* __restrict__ bg2, const float* __restrict__ nw,
              u16* __restrict__ Obf){
  __shared__ u16 Qb[64*132];     // Q, then A' (wave-private rows after prep)
  __shared__ u16 KV[8704];       // K[64][132], then VT[128][68]
  __shared__ u16 Bws[64*132];    // bw*e^{cgm-cg} natural [s][m]
  __shared__ u16 BwT[128*68];    // transposed [m][s]
  __shared__ u16 Ssb[64*68];     // sqk, then P (wave-private rows)
  __shared__ u16 SkL[128*132];   // Sk'^T * e^{cgm[m]}  [m][d]
  __shared__ u16 SvL[128*132];   // Sv'^T * e^{cgm[m]}  [v][m]
  __shared__ float cgm[128];
  __shared__ float ecgm[128];
  const int bx=blockIdx.x, h=bx&15, c=bx>>4, tid=threadIdx.x;
  const int w=tid>>6, lane=tid&63, lr=lane&15, kg=lane>>4;
  const float SCALE = 0.088388347648318447f;   // 128^-0.5
  const f32x4 vz = {0.f,0.f,0.f,0.f};
  if (tid<128){ float t=cg[(size_t)(c*64+31)*2048 + h*128 + tid]; cgm[tid]=t; ecgm[tid]=__expf(t); }
  __syncthreads();
#pragma unroll
  for (int j=0;j<8;j++){
    int f4=tid+j*256, r=f4>>5, c4=(f4&31)<<2;
    size_t g=(size_t)(c*64+r)*2048 + h*128 + c4;
    *(ushort4*)&Qb[r*132+c4] = *(const ushort4*)&q[g];
    *(ushort4*)&KV[r*132+c4] = *(const ushort4*)&k[g];
    ushort4 bv=*(const ushort4*)&bw[g];
    float4 cv=*(const float4*)&cg[g];
    float b0=bf2f(bv.x)*__expf(cgm[c4+0]-cv.x);
    float b1=bf2f(bv.y)*__expf(cgm[c4+1]-cv.y);
    float b2=bf2f(bv.z)*__expf(cgm[c4+2]-cv.z);
    float b3=bf2f(bv.w)*__expf(cgm[c4+3]-cv.w);
    bf16x4 bb = cvt4(b0,b1,b2,b3);
    *(bf16x4*)&Bws[r*132+c4] = bb;
    BwT[(c4+0)*68+r]=(u16)bb[0]; BwT[(c4+1)*68+r]=(u16)bb[1];
    BwT[(c4+2)*68+r]=(u16)bb[2]; BwT[(c4+3)*68+r]=(u16)bb[3];
  }
  __syncthreads();
  {
    f32x4 acc1[4];
#pragma unroll
    for (int a=0;a<4;a++) acc1[a]=vz;
#pragma unroll
    for (int ks=0;ks<4;ks++){
      bf16x8 aq = ldfrag(&Qb[(w*16+lr)*132 + ks*32+kg*8]);
#pragma unroll
      for (int ni=0;ni<4;ni++){
        bf16x8 bk = ldfrag(&KV[(ni*16+lr)*132 + ks*32+kg*8]);
        acc1[ni]=__builtin_amdgcn_mfma_f32_16x16x32_bf16(aq,bk,acc1[ni],0,0,0);
      }
    }
#pragma unroll
    for (int ni=0;ni<4;ni++)
#pragma unroll
      for (int vv2=0;vv2<4;vv2++){
        int row=w*16+kg*4+vv2, col=ni*16+lr;
        Ssb[row*68+col] = (col<=row) ? f2bf(acc1[ni][vv2]) : (u16)0;
      }
  }
  __syncthreads();   // all K reads done -> KV reusable for VT
#pragma unroll
  for (int j=0;j<8;j++){
    int f4=tid+j*256, r=f4>>5, c4=(f4&31)<<2;
    ushort4 vv=*(const ushort4*)&v[(size_t)(c*64+r)*2048 + h*128 + c4];
    KV[(c4+0)*68+r]=vv.x; KV[(c4+1)*68+r]=vv.y;
    KV[(c4+2)*68+r]=vv.z; KV[(c4+3)*68+r]=vv.w;
  }
#pragma unroll
  for (int j=0;j<16;j++){
    int f4=tid+j*256, r=f4>>5, c4=(f4&31)<<2;
    ushort4 s4=*(const ushort4*)&SkT[(size_t)bx*16384 + (size_t)r*128 + c4];
    float em=ecgm[r];
    *(bf16x4*)&SkL[r*132+c4]=cvt4(bf2f(s4.x)*em, bf2f(s4.y)*em, bf2f(s4.z)*em, bf2f(s4.w)*em);
  }
#pragma unroll
  for (int j=0;j<16;j++){
    int f4=tid+j*256, r=f4>>5, c4=(f4&31)<<2;
    ushort4 s4=*(const ushort4*)&SvT[(size_t)bx*16384 + (size_t)r*128 + c4];
    *(bf16x4*)&SvL[r*132+c4]=cvt4(bf2f(s4.x)*ecgm[c4+0], bf2f(s4.y)*ecgm[c4+1],
                                  bf2f(s4.z)*ecgm[c4+2], bf2f(s4.w)*ecgm[c4+3]);
  }
  f32x4 zac[8];
#pragma unroll
  for (int a=0;a<8;a++) zac[a]=vz;
#pragma unroll
  for (int ks=0;ks<2;ks++){
    bf16x8 as_ = ldfrag(&Ssb[(w*16+lr)*68 + ks*32+kg*8]);
#pragma unroll
    for (int ni=0;ni<8;ni++){
      bf16x8 bb = ldfrag(&BwT[(ni*16+lr)*68 + ks*32+kg*8]);
      zac[ni]=__builtin_amdgcn_mfma_f32_16x16x32_bf16(as_,bb,zac[ni],0,0,0);
    }
  }
  __syncthreads();   // SkL/SvL/VT staged & visible
#pragma unroll
  for (int dt=0;dt<4;dt++){
    bf16x8 aq = ldfrag(&Qb[(w*16+lr)*132 + dt*32+kg*8]);
#pragma unroll
    for (int ni=0;ni<8;ni++){
      bf16x8 bs = ldfrag(&SkL[(ni*16+lr)*132 + dt*32+kg*8]);
      zac[ni]=__builtin_amdgcn_mfma_f32_16x16x32_bf16(aq,bs,zac[ni],0,0,0);
    }
  }
  float dec[4][8], zz[4][8];
#pragma unroll
  for (int vv2=0;vv2<4;vv2++)
#pragma unroll
    for (int ni=0;ni<8;ni++) zz[vv2][ni]=zac[ni][vv2];
#pragma unroll
  for (int vv2=0;vv2<4;vv2++){
    size_t gr=(size_t)(c*64+w*16+kg*4+vv2)*2048 + h*128;
#pragma unroll
    for (int ni=0;ni<8;ni++){
      float cgv = cg[gr + ni*16+lr];
      dec[vv2][ni] = __expf(cgv - cgm[ni*16+lr]);
    }
  }
#pragma unroll
  for (int vv2=0;vv2<4;vv2++){
    float mx=-3.0e38f;
#pragma unroll
    for (int ni=0;ni<8;ni++){ zz[vv2][ni] *= SCALE*dec[vv2][ni]; mx=fmaxf(mx,zz[vv2][ni]); }
    mx=fmaxf(mx,__shfl_xor(mx,1)); mx=fmaxf(mx,__shfl_xor(mx,2));
    mx=fmaxf(mx,__shfl_xor(mx,4)); mx=fmaxf(mx,__shfl_xor(mx,8));
    float sum=0.f;
#pragma unroll
    for (int ni=0;ni<8;ni++){ zz[vv2][ni]=__expf(zz[vv2][ni]-mx); sum+=zz[vv2][ni]; }
    sum+=__shfl_xor(sum,1); sum+=__shfl_xor(sum,2);
    sum+=__shfl_xor(sum,4); sum+=__shfl_xor(sum,8);
    float inv=1.f/sum;
#pragma unroll
    for (int ni=0;ni<8;ni++) zz[vv2][ni] *= inv*dec[vv2][ni];   // A' = a * e^{cg-cgm}
  }
#pragma unroll
  for (int vv2=0;vv2<4;vv2++)
#pragma unroll
    for (int ni=0;ni<8;ni++)
      Qb[(w*16+kg*4+vv2)*132 + ni*16+lr] = f2bf(zz[vv2][ni]);
  {
    f32x4 acc4[4];
#pragma unroll
    for (int a=0;a<4;a++) acc4[a]=vz;
#pragma unroll
    for (int ks=0;ks<4;ks++){
      bf16x8 aa = ldfrag(&Qb[(w*16+lr)*132 + ks*32+kg*8]);
#pragma unroll
      for (int ni=0;ni<4;ni++){
        bf16x8 bb = ldfrag(&Bws[(ni*16+lr)*132 + ks*32+kg*8]);
        acc4[ni]=__builtin_amdgcn_mfma_f32_16x16x32_bf16(aa,bb,acc4[ni],0,0,0);
      }
    }
#pragma unroll
    for (int ni=0;ni<4;ni++)
#pragma unroll
      for (int vv2=0;vv2<4;vv2++){
        int row=w*16+kg*4+vv2, col=ni*16+lr;
        Ssb[row*68+col] = (col<=row) ? f2bf(acc4[ni][vv2]) : (u16)0;
      }
  }
  f32x4 oac[8];
#pragma unroll
  for (int a=0;a<8;a++) oac[a]=vz;
#pragma unroll
  for (int ks=0;ks<2;ks++){
    bf16x8 ap = ldfrag(&Ssb[(w*16+lr)*68 + ks*32+kg*8]);
#pragma unroll
    for (int ni=0;ni<8;ni++){
      bf16x8 bv2 = ldfrag(&KV[(ni*16+lr)*68 + ks*32+kg*8]);
      oac[ni]=__builtin_amdgcn_mfma_f32_16x16x32_bf16(ap,bv2,oac[ni],0,0,0);
    }
  }
#pragma unroll
  for (int mt=0;mt<4;mt++){
    bf16x8 aa = ldfrag(&Qb[(w*16+lr)*132 + mt*32+kg*8]);
#pragma unroll
    for (int ni=0;ni<8;ni++){
      bf16x8 bs = ldfrag(&SvL[(ni*16+lr)*132 + mt*32+kg*8]);
      oac[ni]=__builtin_amdgcn_mfma_f32_16x16x32_bf16(aa,bs,oac[ni],0,0,0);
    }
  }
  // ---- fused gated RMSNorm epilogue -> Obf bf16
#pragma unroll
  for (int vv2=0;vv2<4;vv2++){
    float ss = 0.f;
#pragma unroll
    for (int ni=0;ni<8;ni++) ss += oac[ni][vv2]*oac[ni][vv2];
    ss += __shfl_xor(ss,1); ss += __shfl_xor(ss,2);
    ss += __shfl_xor(ss,4); ss += __shfl_xor(ss,8);
    float rr = rsqrtf(ss*(1.f/128.f) + 1e-5f);
    int row = c*64 + w*16 + kg*4 + vv2;
#pragma unroll
    for (int ni=0;ni<8;ni++){
      int colh = ni*16+lr;
      int col  = h*128 + colh;
      float g = bf2f(gate[(size_t)row*2048 + col]) + bg2[col];
      float val = oac[ni][vv2]*rr*nw[colh]*(1.f/(1.f+__expf(-g)));
      Obf[(size_t)row*2048 + col] = f2bf(val);
    }
  }
}

extern "C" void kernel_launch(void* const* d_in, const int* in_sizes, int n_in,
                              void* d_out, int out_size, void* d_ws, size_t ws_size,
                              hipStream_t stream){
  (void)in_sizes; (void)n_in; (void)out_size; (void)ws_size;
  const float* hX   = (const float*)d_in[0];
  const float* Wq   = (const float*)d_in[1];
  const float* Wk   = (const float*)d_in[2];
  const float* Wv   = (const float*)d_in[3];
  const float* Ww   = (const float*)d_in[4];
  const float* cq   = (const float*)d_in[5];
  const float* ck   = (const float*)d_in[6];
  const float* cv   = (const float*)d_in[7];
  const float* Wf1  = (const float*)d_in[8];
  const float* Wf2  = (const float*)d_in[9];
  const float* Wb   = (const float*)d_in[10];
  const float* Wg1  = (const float*)d_in[11];
  const float* Wg2  = (const float*)d_in[12];
  const float* bg2  = (const float*)d_in[13];
  const float* nw   = (const float*)d_in[14];
  const float* Wo   = (const float*)d_in[15];
  char* ws = (char*)d_ws;
  u16*   h_bf  = (u16*)  (ws + 0);                  // 4MB
  u16*   WcatT = (u16*)  (ws + 4194304);            // 32MB, ends 37748736
  u16*   WfgT  = (u16*)  (ws + 37748736);           // 1.5MB, CONTIGUOUS with WcatT (rows 8192..8575)
  u16*   WoT   = (u16*)  (ws + 39321600);           // 8MB
  u16*   Wf2T  = (u16*)  (ws + 47710208);           // 512KB
  u16*   Wg2T  = (u16*)  (ws + 48234496);           // 512KB
  u16*   qkvw  = (u16*)  (ws + 48758784);           // 16MB, dead after conv
  u16*   DSk   = (u16*)  (ws + 48758784);           // 8MB (reuses qkvw)
  u16*   DSv   = (u16*)  (ws + 57147392);           // 8MB
  u16*   gateb = (u16*)  (ws + 65536000);           // 4MB
  u16*   qb    = (u16*)  (ws + 69730304);           // 4MB
  u16*   kb    = (u16*)  (ws + 73924608);           // 4MB
  u16*   vb    = (u16*)  (ws + 78118912);           // 4MB
  u16*   bwb   = (u16*)  (ws + 82313216);           // 4MB
  u16*   f1g1  = (u16*)  (ws + 86507520);           // 768KB [1024][384]
  float* cgb   = (float*)(ws + 87293952);           // 8MB
  float* betab = (float*)(ws + 95682560);           // 64KB
  u16*   Obf   = (u16*)  (ws + 95748096);           // 4MB
  u16*   Sk0   = (u16*)  (ws + 99942400);           // 8MB
  u16*   Sv0   = (u16*)  (ws + 108331008);          // 8MB
  float* outp  = (float*)d_out;

  // conversions: all transposes + hX convert + WbT in ONE launch
  transp64_k<<<dim3(32,32,11),256,0,stream>>>(Wq, Wk, Wv, Ww, Wo, WcatT, WoT, hX, h_bf,
                                              Wf1, Wg1, Wf2, Wg2, Wb, WfgT, Wf2T, Wg2T);

  // G1 fused projection: qkvw (N=8192) + f1g1 (N=384) + beta in one GEMM
  gemmQ_k<<<dim3(67,8),256,0,stream>>>(h_bf, WcatT, qkvw, f1g1, betab, 2048, 2048, 2048);
  gemmg_k<<<dim3(16,8,2),256,0,stream>>>(f1g1, Wf2T, Wg2T, cgb, gateb);   // cg + gate directly

  // conv + silu (+fused l2norm*beta on w-branch), 8 ch/thread
  conv_k<<<1024,256,0,stream>>>(qkvw, cq, ck, cv, betab, qb, kb, vb, bwb);

  // chunked scan (phaseC fuses gated RMSNorm -> Obf)
  phaseA_k<<<256,256,0,stream>>>(kb, vb, bwb, cgb, DSk, DSv);
  phaseB_k<<<2048,256,0,stream>>>(DSk, DSv, cgb, Sk0, Sv0);
  phaseC_k<<<256,256,0,stream>>>(qb, kb, vb, bwb, cgb, Sk0, Sv0, gateb, bg2, nw, Obf);

  // output projection: zero + split-K=2 atomic accumulate (2 commutative adds -> deterministic)
  hipMemsetAsync(outp, 0, (size_t)1024*2048*4, stream);
  gemm4sk_k<<<dim3(16,8,2),256,0,stream>>>(Obf, WoT, outp, 1024, 2048, 2048, 2048);
}

// Round 15
// 172.222 us; speedup vs baseline: 1.1545x; 1.1545x over previous
//
#include <hip/hip_runtime.h>
#include <hip/hip_bf16.h>
#include <stdint.h>

typedef unsigned short u16;
typedef __attribute__((ext_vector_type(8))) short bf16x8;
typedef __attribute__((ext_vector_type(4))) short bf16x4;
typedef __attribute__((ext_vector_type(4))) float f32x4;

#define DEV static __device__ __forceinline__

DEV u16 f2bf(float f){
  union { float f; unsigned u; } x; x.f = f;
  unsigned r = x.u + 0x7fffu + ((x.u >> 16) & 1u);
  return (u16)(r >> 16);
}

DEV float bf2f(u16 u){
  union { unsigned u; float f; } x; x.u = ((unsigned)u) << 16; return x.f;
}

DEV bf16x8 ldfrag(const u16* p){           // two ds_read_b64 (8B-aligned rows)
  bf16x4 a = *(const bf16x4*)p;
  bf16x4 b = *(const bf16x4*)(p+4);
  bf16x8 r;
  r[0]=a[0]; r[1]=a[1]; r[2]=a[2]; r[3]=a[3];
  r[4]=b[0]; r[5]=b[1]; r[6]=b[2]; r[7]=b[3];
  return r;
}

DEV bf16x4 cvt4(float a, float b, float c, float d){
  bf16x4 r; r[0]=(short)f2bf(a); r[1]=(short)f2bf(b); r[2]=(short)f2bf(c); r[3]=(short)f2bf(d);
  return r;
}

DEV void g2l16(const void* g, void* l){
  __builtin_amdgcn_global_load_lds((const __attribute__((address_space(1))) unsigned int*)g,
                                   (__attribute__((address_space(3))) unsigned int*)l,
                                   16, 0, 0);
}

// ---- fused transposes: z=0..4 big 2048x2048, z=5 hX convert, z=6..9 small mats,
// ---- z=10 WbT rows 256..383 of WfgT (rows>=16 zero-padded) ----
__global__ __launch_bounds__(256)
void transp64_k(const float* __restrict__ Wq, const float* __restrict__ Wk,
                const float* __restrict__ Wv, const float* __restrict__ Ww,
                const float* __restrict__ Wo, u16* __restrict__ WcatT, u16* __restrict__ WoT,
                const float* __restrict__ hX, u16* __restrict__ h_bf,
                const float* __restrict__ Wf1, const float* __restrict__ Wg1,
                const float* __restrict__ Wf2, const float* __restrict__ Wg2,
                const float* __restrict__ Wb,
                u16* __restrict__ WfgT, u16* __restrict__ Wf2T, u16* __restrict__ Wg2T){
  __shared__ float tile[64*65];
  const int z = blockIdx.z;
  if (z == 5){
    int idx = ((blockIdx.y*32 + blockIdx.x)*256 + threadIdx.x)*8;
    float4 v0 = *(const float4*)&hX[idx];
    float4 v1 = *(const float4*)&hX[idx+4];
    ushort4 o0, o1;
    o0.x=f2bf(v0.x); o0.y=f2bf(v0.y); o0.z=f2bf(v0.z); o0.w=f2bf(v0.w);
    o1.x=f2bf(v1.x); o1.y=f2bf(v1.y); o1.z=f2bf(v1.z); o1.w=f2bf(v1.w);
    *(ushort4*)&h_bf[idx]   = o0;
    *(ushort4*)&h_bf[idx+4] = o1;
    return;
  }
  if (z == 10){
    int rem = blockIdx.y*32 + blockIdx.x;
    if (rem >= 256) return;
    int cx = rem & 63, cy = rem >> 6;     // k-tile (2048/32), row-tile (128/32)
    const int x = threadIdx.x & 31, y0 = threadIdx.x >> 5;
    int k = cx*32 + x;
#pragma unroll
    for (int j=0;j<4;j++){
      int rpad = cy*32 + y0 + j*8;        // 0..127 -> WfgT row 256+rpad
      float v = (rpad < 16) ? Wb[(size_t)k*16 + rpad] : 0.f;
      WfgT[(size_t)(256+rpad)*2048 + k] = f2bf(v);
    }
    return;
  }
  if (z >= 6){
    int rem = blockIdx.y*32 + blockIdx.x;
    if (rem >= 256) return;
    const float* src; u16* dst; int R, C, cx, cy;
    if (z==6){      src=Wf1; dst=WfgT;                  R=2048; C=128;  cx=rem&3;  cy=rem>>2; }
    else if (z==7){ src=Wg1; dst=WfgT+(size_t)128*2048; R=2048; C=128;  cx=rem&3;  cy=rem>>2; }
    else if (z==8){ src=Wf2; dst=Wf2T;                  R=128;  C=2048; cx=rem>>2; cy=rem&3; }
    else {          src=Wg2; dst=Wg2T;                  R=128;  C=2048; cx=rem>>2; cy=rem&3; }
    const int c0 = cx*32, r0 = cy*32;
    const int x = threadIdx.x & 31, y0 = threadIdx.x >> 5;
#pragma unroll
    for (int j=0;j<4;j++){
      int r = y0 + j*8;
      tile[r*33 + x] = src[(size_t)(r0+r)*C + c0 + x];
    }
    __syncthreads();
#pragma unroll
    for (int j=0;j<4;j++){
      int cc = y0 + j*8;
      dst[(size_t)(c0+cc)*R + r0 + x] = f2bf(tile[x*33 + cc]);
    }
    return;
  }
  const float* src = (z==0)?Wq:((z==1)?Wk:((z==2)?Wv:((z==3)?Ww:Wo)));
  u16* dst = (z<4) ? (WcatT + (size_t)z*4194304) : WoT;
  const int c0 = blockIdx.x*64, r0 = blockIdx.y*64;
#pragma unroll
  for (int p=0;p<4;p++){
    int i = threadIdx.x + p*256;
    int r = i>>4, c4 = (i&15)<<2;
    *(float4*)&tile[r*65 + c4] = *(const float4*)&src[(size_t)(r0+r)*2048 + c0 + c4];
  }
  __syncthreads();
#pragma unroll
  for (int p=0;p<4;p++){
    int i = threadIdx.x + p*256;
    int cc = i>>4, r4 = (i&15)<<2;
    ushort4 o;
    o.x = f2bf(tile[(r4+0)*65 + cc]); o.y = f2bf(tile[(r4+1)*65 + cc]);
    o.z = f2bf(tile[(r4+2)*65 + cc]); o.w = f2bf(tile[(r4+3)*65 + cc]);
    *(ushort4*)&dst[(size_t)(c0+cc)*2048 + r0 + r4] = o;
  }
}

// ---------------- pipelined GEMM: 128x128, BK=64, 4 waves, dbuf + counted vmcnt ----------------
template<bool OBF>
__global__ __launch_bounds__(256)
void gemm4_k(const u16* __restrict__ A, const u16* __restrict__ B, void* __restrict__ Cp,
             int K, int lda, int ldb, int ldc){
  __shared__ u16 As[2][128*64];
  __shared__ u16 Bs[2][128*64];
  const int m0 = blockIdx.y*128, n0 = blockIdx.x*128;
  const int tid = threadIdx.x;
  const int wave = tid>>6, lane = tid&63, lr = lane&15, kg = lane>>4;
  const int wm = wave>>1, wn = wave&1;
  const f32x4 vz = {0.f,0.f,0.f,0.f};
  f32x4 acc[4][4];
#pragma unroll
  for (int a=0;a<4;a++)
#pragma unroll
    for (int b=0;b<4;b++) acc[a][b]=vz;

#define STAGE4(buf, k0) do { \
    _Pragma("unroll") \
    for (int p=0;p<4;p++){ \
      int chunk = tid + p*256, r_ = chunk>>3, ci = chunk&7; \
      g2l16(A + (size_t)(m0+r_)*lda + (k0) + ((ci^(r_&7))<<3), &As[buf][chunk*8]); \
    } \
    _Pragma("unroll") \
    for (int p=0;p<4;p++){ \
      int chunk = tid + p*256, r_ = chunk>>3, ci = chunk&7; \
      g2l16(B + (size_t)(n0+r_)*ldb + (k0) + ((ci^(r_&7))<<3), &Bs[buf][chunk*8]); \
    } \
  } while(0)

  const int nt = K>>6;          // >= 2 required
  STAGE4(0, 0);
  STAGE4(1, 64);
  for (int t=0; t<nt; ++t){
    const int buf = t&1;
    if (t < nt-1) asm volatile("s_waitcnt vmcnt(8)" ::: "memory");
    else          asm volatile("s_waitcnt vmcnt(0)" ::: "memory");
    asm volatile("s_barrier" ::: "memory");
#pragma unroll
    for (int ks=0; ks<2; ++ks){
      bf16x8 af[4], bfv[4];
#pragma unroll
      for (int mi=0;mi<4;mi++){
        int r = wm*64+mi*16+lr;
        af[mi] = *(const bf16x8*)&As[buf][r*64 + (((ks*4+kg)^(r&7))<<3)];
      }
#pragma unroll
      for (int ni=0;ni<4;ni++){
        int r = wn*64+ni*16+lr;
        bfv[ni] = *(const bf16x8*)&Bs[buf][r*64 + (((ks*4+kg)^(r&7))<<3)];
      }
      asm volatile("s_waitcnt lgkmcnt(0)" ::: "memory");
      __builtin_amdgcn_sched_barrier(0);
      __builtin_amdgcn_s_setprio(1);
#pragma unroll
      for (int mi=0;mi<4;mi++)
#pragma unroll
        for (int ni=0;ni<4;ni++)
          acc[mi][ni] = __builtin_amdgcn_mfma_f32_16x16x32_bf16(af[mi], bfv[ni], acc[mi][ni], 0, 0, 0);
      __builtin_amdgcn_s_setprio(0);
      __builtin_amdgcn_sched_barrier(0);
      asm volatile("s_barrier" ::: "memory");
    }
    if (t+2 < nt) STAGE4(buf, (t+2)<<6);
  }
#undef STAGE4
#pragma unroll
  for (int mi=0;mi<4;mi++)
#pragma unroll
    for (int ni=0;ni<4;ni++)
#pragma unroll
      for (int vv=0;vv<4;vv++){
        int row = m0 + wm*64 + mi*16 + kg*4 + vv;
        int col = n0 + wn*64 + ni*16 + lr;
        if (OBF) ((u16*)Cp)[(size_t)row*ldc + col] = f2bf(acc[mi][ni][vv]);
        else     ((float*)Cp)[(size_t)row*ldc + col] = acc[mi][ni][vv];
      }
}

// ---- split-K pipelined GEMM: 128x128, BK=64 -> atomic f32 accumulate into out ----
__global__ __launch_bounds__(256)
void gemm4sk_k(const u16* __restrict__ A, const u16* __restrict__ B, float* __restrict__ out,
               int Khalf, int lda, int ldb, int ldc){
  __shared__ u16 As[2][128*64];
  __shared__ u16 Bs[2][128*64];
  const int m0 = blockIdx.y*128, n0 = blockIdx.x*128;
  const int kbase = blockIdx.z*Khalf;
  const int tid = threadIdx.x;
  const int wave = tid>>6, lane = tid&63, lr = lane&15, kg = lane>>4;
  const int wm = wave>>1, wn = wave&1;
  const f32x4 vz = {0.f,0.f,0.f,0.f};
  f32x4 acc[4][4];
#pragma unroll
  for (int a=0;a<4;a++)
#pragma unroll
    for (int b=0;b<4;b++) acc[a][b]=vz;

#define STAGE4(buf, k0) do { \
    _Pragma("unroll") \
    for (int p=0;p<4;p++){ \
      int chunk = tid + p*256, r_ = chunk>>3, ci = chunk&7; \
      g2l16(A + (size_t)(m0+r_)*lda + (k0) + ((ci^(r_&7))<<3), &As[buf][chunk*8]); \
    } \
    _Pragma("unroll") \
    for (int p=0;p<4;p++){ \
      int chunk = tid + p*256, r_ = chunk>>3, ci = chunk&7; \
      g2l16(B + (size_t)(n0+r_)*ldb + (k0) + ((ci^(r_&7))<<3), &Bs[buf][chunk*8]); \
    } \
  } while(0)

  const int nt = Khalf>>6;      // >= 2 required
  STAGE4(0, kbase);
  STAGE4(1, kbase+64);
  for (int t=0; t<nt; ++t){
    const int buf = t&1;
    if (t < nt-1) asm volatile("s_waitcnt vmcnt(8)" ::: "memory");
    else          asm volatile("s_waitcnt vmcnt(0)" ::: "memory");
    asm volatile("s_barrier" ::: "memory");
#pragma unroll
    for (int ks=0; ks<2; ++ks){
      bf16x8 af[4], bfv[4];
#pragma unroll
      for (int mi=0;mi<4;mi++){
        int r = wm*64+mi*16+lr;
        af[mi] = *(const bf16x8*)&As[buf][r*64 + (((ks*4+kg)^(r&7))<<3)];
      }
#pragma unroll
      for (int ni=0;ni<4;ni++){
        int r = wn*64+ni*16+lr;
        bfv[ni] = *(const bf16x8*)&Bs[buf][r*64 + (((ks*4+kg)^(r&7))<<3)];
      }
      asm volatile("s_waitcnt lgkmcnt(0)" ::: "memory");
      __builtin_amdgcn_sched_barrier(0);
      __builtin_amdgcn_s_setprio(1);
#pragma unroll
      for (int mi=0;mi<4;mi++)
#pragma unroll
        for (int ni=0;ni<4;ni++)
          acc[mi][ni] = __builtin_amdgcn_mfma_f32_16x16x32_bf16(af[mi], bfv[ni], acc[mi][ni], 0, 0, 0);
      __builtin_amdgcn_s_setprio(0);
      __builtin_amdgcn_sched_barrier(0);
      asm volatile("s_barrier" ::: "memory");
    }
    if (t+2 < nt) STAGE4(buf, kbase + ((t+2)<<6));
  }
#undef STAGE4
  // 2 contributions per address (z=0,1); f32 add is commutative -> deterministic
#pragma unroll
  for (int mi=0;mi<4;mi++)
#pragma unroll
    for (int ni=0;ni<4;ni++)
#pragma unroll
      for (int vv=0;vv<4;vv++){
        int row = m0 + wm*64 + mi*16 + kg*4 + vv;
        int col = n0 + wn*64 + ni*16 + lr;
        unsafeAtomicAdd(&out[(size_t)row*ldc + col], acc[mi][ni][vv]);
      }
}

// ---- fused dual gate GEMM (128^2, K=128): z=0 -> logsigmoid+chunk-cumsum -> cgb f32 ;
//      z=1 -> gate -> bf16 ----
__global__ __launch_bounds__(256)
void gemmg_k(const u16* __restrict__ f1g1, const u16* __restrict__ Bf, const u16* __restrict__ Bg,
             float* __restrict__ Ccg, u16* __restrict__ Cgate){
  __shared__ u16 As[128*32];
  __shared__ u16 Bs[128*32];
  const int zz = blockIdx.z;
  const u16* A = f1g1 + zz*128;          // lda = 384
  const u16* B = zz ? Bg : Bf;           // ldb = 128
  const int m0 = blockIdx.y*128, n0 = blockIdx.x*128;
  const int tid = threadIdx.x;
  const int lane = tid & 63, wave = tid >> 6;
  const int wr = wave >> 1, wc = wave & 1;
  const int lr = lane & 15, kg = lane >> 4;
  const f32x4 vzero = {0.f,0.f,0.f,0.f};
  f32x4 acc[4][4];
#pragma unroll
  for (int a=0;a<4;a++)
#pragma unroll
    for (int b=0;b<4;b++) acc[a][b] = vzero;
  const int r0 = tid>>2, s0 = tid&3;
  for (int k0=0;k0<128;k0+=32){
    __syncthreads();
    g2l16(A + (size_t)(m0+r0)*384 + k0 + s0*8, (u16*)As + (size_t)tid*8);
    g2l16(B + (size_t)(n0+r0)*128 + k0 + s0*8, (u16*)Bs + (size_t)tid*8);
    g2l16(A + (size_t)(m0+r0+64)*384 + k0 + s0*8, (u16*)As + (size_t)(tid+256)*8);
    g2l16(B + (size_t)(n0+r0+64)*128 + k0 + s0*8, (u16*)Bs + (size_t)(tid+256)*8);
    __syncthreads();
    bf16x8 af[4], bfv[4];
#pragma unroll
    for (int mi=0;mi<4;mi++) af[mi]  = *(const bf16x8*)(As + (wr*64+mi*16+lr)*32 + kg*8);
#pragma unroll
    for (int ni=0;ni<4;ni++) bfv[ni] = *(const bf16x8*)(Bs + (wc*64+ni*16+lr)*32 + kg*8);
#pragma unroll
    for (int mi=0;mi<4;mi++)
#pragma unroll
      for (int ni=0;ni<4;ni++)
        acc[mi][ni] = __builtin_amdgcn_mfma_f32_16x16x32_bf16(af[mi], bfv[ni], acc[mi][ni], 0, 0, 0);
  }
  if (zz == 0){
    // logsigmoid + inclusive cumsum over the 64-row chunk (wr-aligned) per column
#pragma unroll
    for (int ni=0;ni<4;ni++){
      float p[4][4]; float s[4];
#pragma unroll
      for (int mi=0;mi<4;mi++){
        float run = 0.f;
#pragma unroll
        for (int vv=0;vv<4;vv++){
          float v = acc[mi][ni][vv];
          v = fminf(v,0.f) - __logf(1.f + __expf(-fabsf(v)));
          run += v; p[mi][vv] = run;
        }
        s[mi] = run;
      }
      float M = 0.f; float base[4];
#pragma unroll
      for (int mi=0;mi<4;mi++){
        float a0 = __shfl(s[mi], lr);
        float a1 = __shfl(s[mi], lr+16);
        float a2 = __shfl(s[mi], lr+32);
        float a3 = __shfl(s[mi], lr+48);
        float before = 0.f;
        if (kg>0) before += a0;
        if (kg>1) before += a1;
        if (kg>2) before += a2;
        base[mi] = M + before;
        M += a0+a1+a2+a3;
      }
#pragma unroll
      for (int mi=0;mi<4;mi++)
#pragma unroll
        for (int vv=0;vv<4;vv++){
          int row = m0 + wr*64 + mi*16 + kg*4 + vv;
          int col = n0 + wc*64 + ni*16 + lr;
          Ccg[(size_t)row*2048 + col] = base[mi] + p[mi][vv];
        }
    }
  } else {
#pragma unroll
    for (int mi=0;mi<4;mi++)
#pragma unroll
      for (int ni=0;ni<4;ni++)
#pragma unroll
        for (int vv=0;vv<4;vv++){
          int row = m0 + wr*64 + mi*16 + kg*4 + vv;
          int col = n0 + wc*64 + ni*16 + lr;
          Cgate[(size_t)row*2048 + col] = f2bf(acc[mi][ni][vv]);
        }
  }
}

// ---------------- split-K GEMM for f1g1+beta (N=384, K=2048 in 16 chunks, bf16 partials) ----------------
__global__ __launch_bounds__(256)
void gemmsk_k(const u16* __restrict__ A, const u16* __restrict__ B, u16* __restrict__ P,
              int lda, int ldb){
  __shared__ u16 As[128*32];
  __shared__ u16 Bs[128*32];
  const int m0 = blockIdx.y*128, n0 = blockIdx.x*128;
  const int kbase = blockIdx.z*128;
  const int tid = threadIdx.x;
  const int lane = tid & 63, wave = tid >> 6;
  const int wr = wave >> 1, wc = wave & 1;
  const int lr = lane & 15, kg = lane >> 4;
  const f32x4 vzero = {0.f,0.f,0.f,0.f};
  f32x4 acc[4][4];
#pragma unroll
  for (int a=0;a<4;a++)
#pragma unroll
    for (int b=0;b<4;b++) acc[a][b] = vzero;
  const int r0 = tid>>2, s0 = tid&3;
  for (int k0=kbase;k0<kbase+128;k0+=32){
    __syncthreads();
    g2l16(A + (size_t)(m0+r0)*lda + k0 + s0*8, (u16*)As + (size_t)tid*8);
    g2l16(B + (size_t)(n0+r0)*ldb + k0 + s0*8, (u16*)Bs + (size_t)tid*8);
    g2l16(A + (size_t)(m0+r0+64)*lda + k0 + s0*8, (u16*)As + (size_t)(tid+256)*8);
    g2l16(B + (size_t)(n0+r0+64)*ldb + k0 + s0*8, (u16*)Bs + (size_t)(tid+256)*8);
    __syncthreads();
    bf16x8 af[4], bfv[4];
#pragma unroll
    for (int mi=0;mi<4;mi++) af[mi]  = *(const bf16x8*)(As + (wr*64+mi*16+lr)*32 + kg*8);
#pragma unroll
    for (int ni=0;ni<4;ni++) bfv[ni] = *(const bf16x8*)(Bs + (wc*64+ni*16+lr)*32 + kg*8);
#pragma unroll
    for (int mi=0;mi<4;mi++)
#pragma unroll
      for (int ni=0;ni<4;ni++)
        acc[mi][ni] = __builtin_amdgcn_mfma_f32_16x16x32_bf16(af[mi], bfv[ni], acc[mi][ni], 0, 0, 0);
  }
#pragma unroll
  for (int mi=0;mi<4;mi++)
#pragma unroll
    for (int ni=0;ni<4;ni++)
#pragma unroll
      for (int vv=0;vv<4;vv++){
        int row = m0 + wr*64 + mi*16 + kg*4 + vv;
        int col = n0 + wc*64 + ni*16 + lr;
        P[(size_t)blockIdx.z*393216 + (size_t)row*384 + col] = f2bf(acc[mi][ni][vv]);
      }
}

// ---- reduce 16 bf16 partials -> f1g1 bf16 [1024][384]; cols 256..271 -> sigmoid -> betab ----
__global__ __launch_bounds__(256)
void reduceb_k(const u16* __restrict__ P, u16* __restrict__ out, float* __restrict__ betab){
  int i4 = (blockIdx.x*256 + threadIdx.x)*4;
  float s0=0.f, s1=0.f, s2=0.f, s3=0.f;
#pragma unroll
  for (int z=0;z<16;z++){
    ushort4 p = *(const ushort4*)&P[(size_t)z*393216 + i4];
    s0+=bf2f(p.x); s1+=bf2f(p.y); s2+=bf2f(p.z); s3+=bf2f(p.w);
  }
  ushort4 o; o.x=f2bf(s0); o.y=f2bf(s1); o.z=f2bf(s2); o.w=f2bf(s3);
  *(ushort4*)&out[i4] = o;
  int col = i4 % 384;
  if (col >= 256 && col < 272){
    int row = i4 / 384;
    float* bp = &betab[row*16 + (col-256)];
    bp[0] = 1.f/(1.f+__expf(-s0));
    bp[1] = 1.f/(1.f+__expf(-s1));
    bp[2] = 1.f/(1.f+__expf(-s2));
    bp[3] = 1.f/(1.f+__expf(-s3));
  }
}

// ---- causal conv4 + silu, 8 ch/thread: q,k,v -> bf16 ; w-branch -> l2norm*beta -> bwb bf16 ----
__global__ __launch_bounds__(256)
void conv_k(const u16* __restrict__ raw, const float* __restrict__ cq,
            const float* __restrict__ ck, const float* __restrict__ cv,
            const float* __restrict__ betab,
            u16* __restrict__ qo, u16* __restrict__ ko,
            u16* __restrict__ vo, u16* __restrict__ bwout){
  int idx = blockIdx.x*256 + threadIdx.x;      // 262144 total
  int g8 = idx & 1023;                          // channel-group (8 ch)
  int tb = idx >> 10;                           // t-block, t0 = tb*4
  int chg = g8*8;
  int which = chg >> 11, cc = chg & 2047;
  const float* wt = (which==0)?cq:((which==1)?ck:cv);   // w-branch (3) uses cv (faithful to ref)
  float w[8][4];
#pragma unroll
  for (int e=0;e<8;e++){
    float4 w4 = *(const float4*)&wt[(cc+e)*4];
    w[e][0]=w4.x; w[e][1]=w4.y; w[e][2]=w4.z; w[e][3]=w4.w;
  }
  int t0 = tb*4;
  float x[7][8];
#pragma unroll
  for (int j=0;j<7;j++){
    int t = t0 - 3 + j;
    if (t >= 0){
      bf16x8 xv = *(const bf16x8*)&raw[(size_t)t*8192 + chg];
#pragma unroll
      for (int e=0;e<8;e++) x[j][e] = bf2f((u16)xv[e]);
    } else {
#pragma unroll
      for (int e=0;e<8;e++) x[j][e] = 0.f;
    }
  }
  float y[4][8];
#pragma unroll
  for (int j=0;j<4;j++)
#pragma unroll
    for (int e=0;e<8;e++){
      float a = x[j][e]*w[e][0] + x[j+1][e]*w[e][1] + x[j+2][e]*w[e][2] + x[j+3][e]*w[e][3];
      y[j][e] = a/(1.f+__expf(-a));             // silu
    }
  if (which < 3){
    u16* outb = (which==0)?qo:((which==1)?ko:vo);
#pragma unroll
    for (int j=0;j<4;j++){
      bf16x8 o;
#pragma unroll
      for (int e=0;e<8;e++) o[e] = (short)f2bf(y[j][e]);
      *(bf16x8*)&outb[(size_t)(t0+j)*2048 + cc] = o;
    }
  } else {
    // l2norm over head (128 ch = 16 lanes x 8): shfl within aligned 16-lane group
    const int h = cc >> 7;
#pragma unroll
    for (int j=0;j<4;j++){
      float s = 0.f;
#pragma unroll
      for (int e=0;e<8;e++) s += y[j][e]*y[j][e];
      s += __shfl_xor(s,1); s += __shfl_xor(s,2);
      s += __shfl_xor(s,4); s += __shfl_xor(s,8);
      float r = rsqrtf(s + 1e-6f) * betab[(t0+j)*16 + h];
      bf16x8 o;
#pragma unroll
      for (int e=0;e<8;e++) o[e] = (short)f2bf(y[j][e]*r);
      *(bf16x8*)&bwout[(size_t)(t0+j)*2048 + cc] = o;
    }
  }
}

// ---------------- Phase A (MFMA): DSkT[m][d] = U^T K ; DSvT[v][m] = V^T U (bf16 out) ----------------
__global__ __launch_bounds__(256)
void phaseA_k(const u16* __restrict__ k, const u16* __restrict__ v,
              const u16* __restrict__ bw, const float* __restrict__ cg,
              u16* __restrict__ DSkT, u16* __restrict__ DSvT){
  __shared__ u16 UT[128*68];
  __shared__ u16 KT[128*68];
  __shared__ u16 VT[128*68];
  __shared__ float Gt[128];
  const int bx=blockIdx.x, h=bx&15, c=bx>>4, tid=threadIdx.x;
  const int w=tid>>6, lane=tid&63, lr=lane&15, kg=lane>>4;
  if (tid<128) Gt[tid] = cg[(size_t)(c*64+63)*2048 + h*128 + tid];
  __syncthreads();
#pragma unroll
  for (int j=0;j<8;j++){
    int f4=tid+j*256, r=f4>>5, c4=(f4&31)<<2;
    size_t g=(size_t)(c*64+r)*2048 + h*128 + c4;
    ushort4 kv=*(const ushort4*)&k[g];
    ushort4 vv=*(const ushort4*)&v[g];
    ushort4 bv=*(const ushort4*)&bw[g];
    float4 cv=*(const float4*)&cg[g];
    float u0=bf2f(bv.x)*__expf(Gt[c4+0]-cv.x);
    float u1=bf2f(bv.y)*__expf(Gt[c4+1]-cv.y);
    float u2=bf2f(bv.z)*__expf(Gt[c4+2]-cv.z);
    float u3=bf2f(bv.w)*__expf(Gt[c4+3]-cv.w);
    KT[(c4+0)*68+r]=kv.x; KT[(c4+1)*68+r]=kv.y;
    KT[(c4+2)*68+r]=kv.z; KT[(c4+3)*68+r]=kv.w;
    VT[(c4+0)*68+r]=vv.x; VT[(c4+1)*68+r]=vv.y;
    VT[(c4+2)*68+r]=vv.z; VT[(c4+3)*68+r]=vv.w;
    UT[(c4+0)*68+r]=f2bf(u0);   UT[(c4+1)*68+r]=f2bf(u1);
    UT[(c4+2)*68+r]=f2bf(u2);   UT[(c4+3)*68+r]=f2bf(u3);
  }
  __syncthreads();
  const f32x4 vz = {0.f,0.f,0.f,0.f};
  {
    f32x4 acc[2][8];
#pragma unroll
    for (int a=0;a<2;a++)
#pragma unroll
      for (int b=0;b<8;b++) acc[a][b]=vz;
#pragma unroll
    for (int ks=0;ks<2;ks++){
      bf16x8 a0=ldfrag(&UT[(w*32   +lr)*68 + ks*32+kg*8]);
      bf16x8 a1=ldfrag(&UT[(w*32+16+lr)*68 + ks*32+kg*8]);
#pragma unroll
      for (int nj=0;nj<8;nj++){
        bf16x8 b=ldfrag(&KT[(nj*16+lr)*68 + ks*32+kg*8]);
        acc[0][nj]=__builtin_amdgcn_mfma_f32_16x16x32_bf16(a0,b,acc[0][nj],0,0,0);
        acc[1][nj]=__builtin_amdgcn_mfma_f32_16x16x32_bf16(a1,b,acc[1][nj],0,0,0);
      }
    }
#pragma unroll
    for (int mi2=0;mi2<2;mi2++)
#pragma unroll
      for (int nj=0;nj<8;nj++)
#pragma unroll
        for (int vv2=0;vv2<4;vv2++)
          DSkT[(size_t)bx*16384 + (size_t)(w*32+mi2*16+kg*4+vv2)*128 + nj*16+lr] = f2bf(acc[mi2][nj][vv2]);
  }
  {
    f32x4 acc[2][8];
#pragma unroll
    for (int a=0;a<2;a++)
#pragma unroll
      for (int b=0;b<8;b++) acc[a][b]=vz;
#pragma unroll
    for (int ks=0;ks<2;ks++){
      bf16x8 a0=ldfrag(&VT[(w*32   +lr)*68 + ks*32+kg*8]);
      bf16x8 a1=ldfrag(&VT[(w*32+16+lr)*68 + ks*32+kg*8]);
#pragma unroll
      for (int nj=0;nj<8;nj++){
        bf16x8 b=ldfrag(&UT[(nj*16+lr)*68 + ks*32+kg*8]);
        acc[0][nj]=__builtin_amdgcn_mfma_f32_16x16x32_bf16(a0,b,acc[0][nj],0,0,0);
        acc[1][nj]=__builtin_amdgcn_mfma_f32_16x16x32_bf16(a1,b,acc[1][nj],0,0,0);
      }
    }
#pragma unroll
    for (int mi2=0;mi2<2;mi2++)
#pragma unroll
      for (int nj=0;nj<8;nj++)
#pragma unroll
        for (int vv2=0;vv2<4;vv2++)
          DSvT[(size_t)bx*16384 + (size_t)(w*32+mi2*16+kg*4+vv2)*128 + nj*16+lr] = f2bf(acc[mi2][nj][vv2]);
  }
}

// ---------------- Phase B: sequential cross-chunk combine (bf16 in/out) ----------------
__global__ __launch_bounds__(256)
void phaseB_k(const u16* __restrict__ DSk, const u16* __restrict__ DSv,
              const float* __restrict__ cg, u16* __restrict__ Sk0, u16* __restrict__ Sv0){
  unsigned idx = blockIdx.x*256u + threadIdx.x;   // 524288 total
  int sel  = idx >> 18;
  int h    = (idx >> 14) & 15;
  int flat = idx & 16383;                 // SkT: m*128+d ; SvT: v*128+m
  int mdec = sel ? (flat & 127) : (flat >> 7);
  const u16* DS = sel ? DSv : DSk;
  u16* S = sel ? Sv0 : Sk0;
  float cur = 0.f;
  for (int c=0;c<16;c++){
    size_t sb = ((size_t)(c*16+h))*16384 + flat;
    S[sb] = f2bf(cur);                     // state BEFORE chunk c
    float gd = __expf(cg[(size_t)(c*64+63)*2048 + h*128 + mdec]);
    cur = cur*gd + bf2f(DS[sb]);
  }
}

// ---------------- Phase C (MFMA): per-chunk outputs + fused gated RMSNorm -> Obf ----------------
__global__ __launch_bounds__(256)
void phaseC_k(const u16* __restrict__ q, const u16* __restrict__ k,
              const u16* __restrict__ v, const u16* __restrict__ bw,
              const float* __restrict__ cg, const u16* __restrict__ SkT,
              const u16* __restrict__ SvT, const u16* __restrict__ gate,
              const float* __restrict__ bg2, const float* __restrict__ nw,
              u16* __restrict__ Obf){
  __shared__ u16 Qb[64*132];     // Q, then A' (wave-private rows after prep)
  __shared__ u16 KV[8704];       // K[64][132], then VT[128][68]
  __shared__ u16 Bws[64*132];    // bw*e^{cgm-cg} natural [s][m]
  __shared__ u16 BwT[128*68];    // transposed [m][s]
  __shared__ u16 Ssb[64*68];     // sqk, then P (wave-private rows)
  __shared__ u16 SkL[128*132];   // Sk'^T * e^{cgm[m]}  [m][d]
  __shared__ u16 SvL[128*132];   // Sv'^T * e^{cgm[m]}  [v][m]
  __shared__ float cgm[128];
  __shared__ float ecgm[128];
  const int bx=blockIdx.x, h=bx&15, c=bx>>4, tid=threadIdx.x;
  const int w=tid>>6, lane=tid&63, lr=lane&15, kg=lane>>4;
  const float SCALE = 0.088388347648318447f;   // 128^-0.5
  const f32x4 vz = {0.f,0.f,0.f,0.f};
  if (tid<128){ float t=cg[(size_t)(c*64+31)*2048 + h*128 + tid]; cgm[tid]=t; ecgm[tid]=__expf(t); }
  __syncthreads();
#pragma unroll
  for (int j=0;j<8;j++){
    int f4=tid+j*256, r=f4>>5, c4=(f4&31)<<2;
    size_t g=(size_t)(c*64+r)*2048 + h*128 + c4;
    *(ushort4*)&Qb[r*132+c4] = *(const ushort4*)&q[g];
    *(ushort4*)&KV[r*132+c4] = *(const ushort4*)&k[g];
    ushort4 bv=*(const ushort4*)&bw[g];
    float4 cv=*(const float4*)&cg[g];
    float b0=bf2f(bv.x)*__expf(cgm[c4+0]-cv.x);
    float b1=bf2f(bv.y)*__expf(cgm[c4+1]-cv.y);
    float b2=bf2f(bv.z)*__expf(cgm[c4+2]-cv.z);
    float b3=bf2f(bv.w)*__expf(cgm[c4+3]-cv.w);
    bf16x4 bb = cvt4(b0,b1,b2,b3);
    *(bf16x4*)&Bws[r*132+c4] = bb;
    BwT[(c4+0)*68+r]=(u16)bb[0]; BwT[(c4+1)*68+r]=(u16)bb[1];
    BwT[(c4+2)*68+r]=(u16)bb[2]; BwT[(c4+3)*68+r]=(u16)bb[3];
  }
  __syncthreads();
  {
    f32x4 acc1[4];
#pragma unroll
    for (int a=0;a<4;a++) acc1[a]=vz;
#pragma unroll
    for (int ks=0;ks<4;ks++){
      bf16x8 aq = ldfrag(&Qb[(w*16+lr)*132 + ks*32+kg*8]);
#pragma unroll
      for (int ni=0;ni<4;ni++){
        bf16x8 bk = ldfrag(&KV[(ni*16+lr)*132 + ks*32+kg*8]);
        acc1[ni]=__builtin_amdgcn_mfma_f32_16x16x32_bf16(aq,bk,acc1[ni],0,0,0);
      }
    }
#pragma unroll
    for (int ni=0;ni<4;ni++)
#pragma unroll
      for (int vv2=0;vv2<4;vv2++){
        int row=w*16+kg*4+vv2, col=ni*16+lr;
        Ssb[row*68+col] = (col<=row) ? f2bf(acc1[ni][vv2]) : (u16)0;
      }
  }
  __syncthreads();   // all K reads done -> KV reusable for VT
#pragma unroll
  for (int j=0;j<8;j++){
    int f4=tid+j*256, r=f4>>5, c4=(f4&31)<<2;
    ushort4 vv=*(const ushort4*)&v[(size_t)(c*64+r)*2048 + h*128 + c4];
    KV[(c4+0)*68+r]=vv.x; KV[(c4+1)*68+r]=vv.y;
    KV[(c4+2)*68+r]=vv.z; KV[(c4+3)*68+r]=vv.w;
  }
#pragma unroll
  for (int j=0;j<16;j++){
    int f4=tid+j*256, r=f4>>5, c4=(f4&31)<<2;
    ushort4 s4=*(const ushort4*)&SkT[(size_t)bx*16384 + (size_t)r*128 + c4];
    float em=ecgm[r];
    *(bf16x4*)&SkL[r*132+c4]=cvt4(bf2f(s4.x)*em, bf2f(s4.y)*em, bf2f(s4.z)*em, bf2f(s4.w)*em);
  }
#pragma unroll
  for (int j=0;j<16;j++){
    int f4=tid+j*256, r=f4>>5, c4=(f4&31)<<2;
    ushort4 s4=*(const ushort4*)&SvT[(size_t)bx*16384 + (size_t)r*128 + c4];
    *(bf16x4*)&SvL[r*132+c4]=cvt4(bf2f(s4.x)*ecgm[c4+0], bf2f(s4.y)*ecgm[c4+1],
                                  bf2f(s4.z)*ecgm[c4+2], bf2f(s4.w)*ecgm[c4+3]);
  }
  f32x4 zac[8];
#pragma unroll
  for (int a=0;a<8;a++) zac[a]=vz;
#pragma unroll
  for (int ks=0;ks<2;ks++){
    bf16x8 as_ = ldfrag(&Ssb[(w*16+lr)*68 + ks*32+kg*8]);
#pragma unroll
    for (int ni=0;ni<8;ni++){
      bf16x8 bb = ldfrag(&BwT[(ni*16+lr)*68 + ks*32+kg*8]);
      zac[ni]=__builtin_amdgcn_mfma_f32_16x16x32_bf16(as_,bb,zac[ni],0,0,0);
    }
  }
  __syncthreads();   // SkL/SvL/VT staged & visible
#pragma unroll
  for (int dt=0;dt<4;dt++){
    bf16x8 aq = ldfrag(&Qb[(w*16+lr)*132 + dt*32+kg*8]);
#pragma unroll
    for (int ni=0;ni<8;ni++){
      bf16x8 bs = ldfrag(&SkL[(ni*16+lr)*132 + dt*32+kg*8]);
      zac[ni]=__builtin_amdgcn_mfma_f32_16x16x32_bf16(aq,bs,zac[ni],0,0,0);
    }
  }
  float dec[4][8], zz[4][8];
#pragma unroll
  for (int vv2=0;vv2<4;vv2++)
#pragma unroll
    for (int ni=0;ni<8;ni++) zz[vv2][ni]=zac[ni][vv2];
#pragma unroll
  for (int vv2=0;vv2<4;vv2++){
    size_t gr=(size_t)(c*64+w*16+kg*4+vv2)*2048 + h*128;
#pragma unroll
    for (int ni=0;ni<8;ni++){
      float cgv = cg[gr + ni*16+lr];
      dec[vv2][ni] = __expf(cgv - cgm[ni*16+lr]);
    }
  }
#pragma unroll
  for (int vv2=0;vv2<4;vv2++){
    float mx=-3.0e38f;
#pragma unroll
    for (int ni=0;ni<8;ni++){ zz[vv2][ni] *= SCALE*dec[vv2][ni]; mx=fmaxf(mx,zz[vv2][ni]); }
    mx=fmaxf(mx,__shfl_xor(mx,1)); mx=fmaxf(mx,__shfl_xor(mx,2));
    mx=fmaxf(mx,__shfl_xor(mx,4)); mx=fmaxf(mx,__shfl_xor(mx,8));
    float sum=0.f;
#pragma unroll
    for (int ni=0;ni<8;ni++){ zz[vv2][ni]=__expf(zz[vv2][ni]-mx); sum+=zz[vv2][ni]; }
    sum+=__shfl_xor(sum,1); sum+=__shfl_xor(sum,2);
    sum+=__shfl_xor(sum,4); sum+=__shfl_xor(sum,8);
    float inv=1.f/sum;
#pragma unroll
    for (int ni=0;ni<8;ni++) zz[vv2][ni] *= inv*dec[vv2][ni];   // A' = a * e^{cg-cgm}
  }
#pragma unroll
  for (int vv2=0;vv2<4;vv2++)
#pragma unroll
    for (int ni=0;ni<8;ni++)
      Qb[(w*16+kg*4+vv2)*132 + ni*16+lr] = f2bf(zz[vv2][ni]);
  {
    f32x4 acc4[4];
#pragma unroll
    for (int a=0;a<4;a++) acc4[a]=vz;
#pragma unroll
    for (int ks=0;ks<4;ks++){
      bf16x8 aa = ldfrag(&Qb[(w*16+lr)*132 + ks*32+kg*8]);
#pragma unroll
      for (int ni=0;ni<4;ni++){
        bf16x8 bb = ldfrag(&Bws[(ni*16+lr)*132 + ks*32+kg*8]);
        acc4[ni]=__builtin_amdgcn_mfma_f32_16x16x32_bf16(aa,bb,acc4[ni],0,0,0);
      }
    }
#pragma unroll
    for (int ni=0;ni<4;ni++)
#pragma unroll
      for (int vv2=0;vv2<4;vv2++){
        int row=w*16+kg*4+vv2, col=ni*16+lr;
        Ssb[row*68+col] = (col<=row) ? f2bf(acc4[ni][vv2]) : (u16)0;
      }
  }
  f32x4 oac[8];
#pragma unroll
  for (int a=0;a<8;a++) oac[a]=vz;
#pragma unroll
  for (int ks=0;ks<2;ks++){
    bf16x8 ap = ldfrag(&Ssb[(w*16+lr)*68 + ks*32+kg*8]);
#pragma unroll
    for (int ni=0;ni<8;ni++){
      bf16x8 bv2 = ldfrag(&KV[(ni*16+lr)*68 + ks*32+kg*8]);
      oac[ni]=__builtin_amdgcn_mfma_f32_16x16x32_bf16(ap,bv2,oac[ni],0,0,0);
    }
  }
#pragma unroll
  for (int mt=0;mt<4;mt++){
    bf16x8 aa = ldfrag(&Qb[(w*16+lr)*132 + mt*32+kg*8]);
#pragma unroll
    for (int ni=0;ni<8;ni++){
      bf16x8 bs = ldfrag(&SvL[(ni*16+lr)*132 + mt*32+kg*8]);
      oac[ni]=__builtin_amdgcn_mfma_f32_16x16x32_bf16(aa,bs,oac[ni],0,0,0);
    }
  }
  // ---- fused gated RMSNorm epilogue -> Obf bf16
#pragma unroll
  for (int vv2=0;vv2<4;vv2++){
    float ss = 0.f;
#pragma unroll
    for (int ni=0;ni<8;ni++) ss += oac[ni][vv2]*oac[ni][vv2];
    ss += __shfl_xor(ss,1); ss += __shfl_xor(ss,2);
    ss += __shfl_xor(ss,4); ss += __shfl_xor(ss,8);
    float rr = rsqrtf(ss*(1.f/128.f) + 1e-5f);
    int row = c*64 + w*16 + kg*4 + vv2;
#pragma unroll
    for (int ni=0;ni<8;ni++){
      int colh = ni*16+lr;
      int col  = h*128 + colh;
      float g = bf2f(gate[(size_t)row*2048 + col]) + bg2[col];
      float val = oac[ni][vv2]*rr*nw[colh]*(1.f/(1.f+__expf(-g)));
      Obf[(size_t)row*2048 + col] = f2bf(val);
    }
  }
}

extern "C" void kernel_launch(void* const* d_in, const int* in_sizes, int n_in,
                              void* d_out, int out_size, void* d_ws, size_t ws_size,
                              hipStream_t stream){
  (void)in_sizes; (void)n_in; (void)out_size; (void)ws_size;
  const float* hX   = (const float*)d_in[0];
  const float* Wq   = (const float*)d_in[1];
  const float* Wk   = (const float*)d_in[2];
  const float* Wv   = (const float*)d_in[3];
  const float* Ww   = (const float*)d_in[4];
  const float* cq   = (const float*)d_in[5];
  const float* ck   = (const float*)d_in[6];
  const float* cv   = (const float*)d_in[7];
  const float* Wf1  = (const float*)d_in[8];
  const float* Wf2  = (const float*)d_in[9];
  const float* Wb   = (const float*)d_in[10];
  const float* Wg1  = (const float*)d_in[11];
  const float* Wg2  = (const float*)d_in[12];
  const float* bg2  = (const float*)d_in[13];
  const float* nw   = (const float*)d_in[14];
  const float* Wo   = (const float*)d_in[15];
  char* ws = (char*)d_ws;
  u16*   h_bf  = (u16*)  (ws + 0);
  u16*   WcatT = (u16*)  (ws + 4194304);
  u16*   Sk0   = (u16*)  (ws + 4194304);            // reuses WcatT after GEMMs (bf16)
  u16*   Sv0   = (u16*)  (ws + 20971520);
  u16*   WoT   = (u16*)  (ws + 37748736);
  u16*   Wf2T  = (u16*)  (ws + 47185920);
  u16*   Wg2T  = (u16*)  (ws + 47710208);
  u16*   qkvw  = (u16*)  (ws + 48234496);           // bf16 [1024][8192] -> ends 65011712
  u16*   DSk   = (u16*)  (ws + 48234496);           // bf16, reuses qkvw after conv
  u16*   DSv   = (u16*)  (ws + 56623104);
  u16*   gateb = (u16*)  (ws + 65011712);           // bf16 [1024][2048]
  u16*   qb    = (u16*)  (ws + 81788928);           // bf16 [1024][2048]
  u16*   kb    = (u16*)  (ws + 90177536);
  u16*   vb    = (u16*)  (ws + 98566144);
  u16*   P8    = (u16*)  (ws + 106954752);          // f1g1 split-K bf16 partials (16 x 768KB)
  u16*   bwb   = (u16*)  (ws + 119537664);          // bf16 [1024][2048] (after P8)
  u16*   f1g1  = (u16*)  (ws + 123731968);          // bf16 [1024][384]
  u16*   WfgT  = (u16*)  (ws + 124518400);          // bf16 [384][2048]
  float* cgb   = (float*)(ws + 132644864);
  float* betab = (float*)(ws + 141033472);
  u16*   Obf   = (u16*)  (ws + 141099008);
  float* outp  = (float*)d_out;

  // conversions: all transposes + hX convert + WbT in ONE launch
  transp64_k<<<dim3(32,32,11),256,0,stream>>>(Wq, Wk, Wv, Ww, Wo, WcatT, WoT, hX, h_bf,
                                              Wf1, Wg1, Wf2, Wg2, Wb, WfgT, Wf2T, Wg2T);

  // projections (G1 at 64 n-tiles: n-tiles % 8 == 0 preserves per-XCD L2 panel residency)
  gemm4_k<true><<<dim3(64,8),256,0,stream>>>(h_bf, WcatT, qkvw, 2048, 2048, 2048, 8192);
  gemmsk_k<<<dim3(3,8,16),256,0,stream>>>(h_bf, WfgT, P8, 2048, 2048);
  reduceb_k<<<384,256,0,stream>>>(P8, f1g1, betab);
  gemmg_k<<<dim3(16,8,2),256,0,stream>>>(f1g1, Wf2T, Wg2T, cgb, gateb);   // cg + gate directly

  // conv + silu (+fused l2norm*beta on w-branch), 8 ch/thread
  conv_k<<<1024,256,0,stream>>>(qkvw, cq, ck, cv, betab, qb, kb, vb, bwb);

  // chunked scan (phaseC fuses gated RMSNorm -> Obf)
  phaseA_k<<<256,256,0,stream>>>(kb, vb, bwb, cgb, DSk, DSv);
  phaseB_k<<<2048,256,0,stream>>>(DSk, DSv, cgb, Sk0, Sv0);
  phaseC_k<<<256,256,0,stream>>>(qb, kb, vb, bwb, cgb, Sk0, Sv0, gateb, bg2, nw, Obf);

  // output projection: zero + split-K=2 atomic accumulate (2 commutative adds -> deterministic)
  hipMemsetAsync(outp, 0, (size_t)1024*2048*4, stream);
  gemm4sk_k<<<dim3(16,8,2),256,0,stream>>>(Obf, WoT, outp, 1024, 2048, 2048, 2048);
}